// Round 9
// baseline (5036.086 us; speedup 1.0000x reference)
//
#include <hip/hip_runtime.h>
#include <stdint.h>

#define TSTEPS 500
#define NB 128
#define NH 256
#define RINGN 8
#define NWG 16   // workgroups per layer (each: 16 units x 4 gates = 64 gate-cols)

typedef _Float16 f16;
typedef _Float16 f16x8 __attribute__((ext_vector_type(8)));
typedef float f32x4 __attribute__((ext_vector_type(4)));
typedef unsigned long long u64;
typedef unsigned int u32;

// ---------------- workspace layout ----------------
static constexpr size_t HSLOT = (size_t)NB*NH;                      // 32768 f16 per (layer,t)
static constexpr size_t SZ_XCAT  = (size_t)TSTEPS*NB*256*2;         // 32.77 MB
static constexpr size_t SZ_WLDS  = (size_t)6*NWG*64*256*2;          // 3.15 MB input-half LDS image
static constexpr size_t SZ_WREG  = (size_t)6*NWG*4*8*64*8*2;        // 3.15 MB rec-half reg image
static constexpr size_t SZ_BIAS  = (size_t)6*NWG*64*4;
static constexpr size_t SZ_HNEXT = (size_t)6*RINGN*HSLOT*2;         // MALL-coherent ring
static constexpr size_t SZ_HLOC  = (size_t)6*RINGN*HSLOT*2;         // XCD-local L2 ring
static constexpr size_t SZ_FLAG  = (size_t)6*(TSTEPS+1)*64*4;       // per-wave flags (16wg x 4wv)
static constexpr size_t SZ_RNN   = (size_t)NB*512*4;
static constexpr size_t OFF_XCAT  = 0;
static constexpr size_t OFF_WLDS  = OFF_XCAT + SZ_XCAT;
static constexpr size_t OFF_WREG  = OFF_WLDS + SZ_WLDS;
static constexpr size_t OFF_BIAS  = OFF_WREG + SZ_WREG;
static constexpr size_t OFF_HNEXT = OFF_BIAS + SZ_BIAS;
static constexpr size_t OFF_HLOC  = OFF_HNEXT + SZ_HNEXT;
static constexpr size_t OFF_FLAGL = OFF_HLOC + SZ_HLOC;
static constexpr size_t OFF_FLAGN = OFF_FLAGL + SZ_FLAG;
static constexpr size_t OFF_RNN   = (OFF_FLAGN + SZ_FLAG + 255) & ~(size_t)255;
static constexpr size_t WS_NEED   = OFF_RNN + SZ_RNN;               // ~47.4 MB

// ---------------- prep: embed + concat + pad, cast f16 ----------------
__global__ void embed_kernel(const int* __restrict__ words,
                             const int* __restrict__ caps,
                             const float* __restrict__ emb,
                             const float* __restrict__ capt,
                             f16* __restrict__ xcat) {
  int t = blockIdx.x >> 7, b = blockIdx.x & 127, k = threadIdx.x;
  int w  = words[b*TSTEPS + t];
  int cp = caps [b*TSTEPS + t];
  float v = 0.f;
  if (k < 200)      v = emb[(size_t)w*200 + k];
  else if (k < 203) v = capt[cp*3 + (k-200)];
  xcat[((size_t)t*NB + b)*256 + k] = (f16)v;
}

// ---------------- prep: pack weights (R8-proven) ----------------
__global__ void pack_kernel(const float* __restrict__ Wf0, const float* __restrict__ bf0,
                            const float* __restrict__ Wf1, const float* __restrict__ bf1,
                            const float* __restrict__ Wf2, const float* __restrict__ bf2,
                            const float* __restrict__ Wb0, const float* __restrict__ bb0,
                            const float* __restrict__ Wb1, const float* __restrict__ bb1,
                            const float* __restrict__ Wb2, const float* __restrict__ bb2,
                            f16* __restrict__ wlds, f16* __restrict__ wreg,
                            float* __restrict__ bias) {
  int bid = blockIdx.x;
  int layer, wg;
  const float* W; const float* bb;
  int part1 = (bid < 6144);
  if (part1) layer = bid >> 10;
  else       layer = (bid - 6144) >> 6;
  switch (layer) {
    case 0: W = Wf0; bb = bf0; break;
    case 1: W = Wf1; bb = bf1; break;
    case 2: W = Wf2; bb = bf2; break;
    case 3: W = Wb0; bb = bb0; break;
    case 4: W = Wb1; bb = bb1; break;
    default: W = Wb2; bb = bb2; break;
  }
  int level = layer % 3;
  if (part1) {
    wg = (bid >> 6) & 15;
    int n = bid & 63;
    int g = n >> 4, u = n & 15;
    int col = g*256 + wg*16 + u;
    if (threadIdx.x == 0)
      bias[(size_t)(layer*NWG + wg)*64 + n] = bb[col] + (g == 2 ? 1.f : 0.f);
    int k = threadIdx.x;                                    // 0..255
    int row = (level == 0) ? ((k < 203) ? k : -1) : k;
    float v = (row < 0) ? 0.f : W[(size_t)row*1024 + col];
    int idx = (((k >> 3) ^ (n & 7)) << 3) | (k & 7);
    wlds[((size_t)(layer*NWG + wg)*64 + n)*256 + idx] = (f16)v;
  } else {
    int rem = (bid - 6144) & 63;
    wg = rem >> 2;
    int g = rem & 3;
    int lane = threadIdx.x & 63;
    int col = g*256 + wg*16 + (lane & 15);
    int rbase = (level == 0) ? 203 : 256;
    for (int ks = threadIdx.x >> 6; ks < 8; ks += 4) {
      size_t base = ((size_t)((layer*NWG + wg)*4 + g)*8 + ks)*64*8 + (size_t)lane*8;
      #pragma unroll
      for (int j = 0; j < 8; ++j) {
        int k = ks*32 + (lane >> 4)*8 + j;
        wreg[base + j] = (f16)W[(size_t)(rbase + k)*1024 + col];
      }
    }
  }
}

// ---------------- prep: flags + hnext ring slot0 = h_0 = 0 ----------------
__global__ void init_kernel(int* __restrict__ flagL, int* __restrict__ flagN,
                            f16* __restrict__ hnext) {
  int i = blockIdx.x*256 + threadIdx.x;
  if (i < 6*(TSTEPS+1)*64) {
    int t = (i >> 6) % (TSTEPS+1);
    flagL[i] = 0;
    flagN[i] = (t == 0) ? 9 : 0;                  // 9 never matches xcc+1 in [1,8]
  }
  if (i < 98304) {                                // hnext slot 0 = zeros per layer
    int l = i >> 14, e = i & 16383;
    ((u32*)(hnext + (size_t)l*RINGN*HSLOT))[e] = 0u;
  }
}

// ---------------- helpers ----------------
__device__ __forceinline__ int poll_agent(const int* q) {
  int v;
  for (;;) {
    v = __hip_atomic_load(q, __ATOMIC_RELAXED, __HIP_MEMORY_SCOPE_AGENT);
    if (__all(v != 0)) break;
    __builtin_amdgcn_s_sleep(1);
  }
  return v;
}
__device__ __forceinline__ int ld_flag_l(const int* p) {       // sc0: L1-bypass L2 read
  int v;
  asm volatile("global_load_dword %0, %1, off sc0\n\ts_waitcnt vmcnt(0)"
               : "=v"(v) : "v"(p) : "memory");
  return v;
}
__device__ __forceinline__ f16x8 ld_a_l(const f16* p) {        // 16B same-XCD L2 load
  f16x8 v;
  asm volatile("global_load_dwordx4 %0, %1, off sc0" : "=v"(v) : "v"(p));
  return v;
}
__device__ __forceinline__ f16x8 ld_a_p(const f16* p) {        // 16B plain cached load
  f16x8 v;
  asm volatile("global_load_dwordx4 %0, %1, off" : "=v"(v) : "v"(p));
  return v;
}
__device__ __forceinline__ f16x8 ldA_coh(const f16* p) {       // cross-XCD via MALL (proven)
  union { u64 q[2]; f16x8 v; } u;
  u.q[0] = __hip_atomic_load((const u64*)p,     __ATOMIC_RELAXED, __HIP_MEMORY_SCOPE_AGENT);
  u.q[1] = __hip_atomic_load((const u64*)p + 1, __ATOMIC_RELAXED, __HIP_MEMORY_SCOPE_AGENT);
  return u.v;
}
__device__ __forceinline__ void st_h_l(f16* p, short s) {      // plain store -> own-XCD L2
  asm volatile("global_store_short %0, %1, off" :: "v"(p), "v"((int)s) : "memory");
}
__device__ __forceinline__ void st_flag_plain(int* p, int v) {
  asm volatile("global_store_dword %0, %1, off" :: "v"(p), "v"(v) : "memory");
}
__device__ __forceinline__ void vm_wait(int n) {               // literal-count waits
  if (n == 0)      asm volatile("s_waitcnt vmcnt(0)" ::: "memory");
  else if (n == 8) asm volatile("s_waitcnt vmcnt(8)" ::: "memory");
  __builtin_amdgcn_sched_barrier(0);
}
__device__ __forceinline__ float sigf(float x) {
  return __builtin_amdgcn_rcpf(1.f + __expf(-x));
}
__device__ __forceinline__ float tanhf_(float x) {
  float e = __expf(-2.f*fabsf(x));
  float r = (1.f - e) * __builtin_amdgcn_rcpf(1.f + e);
  return x < 0.f ? -r : r;
}

// grid = 128 (layer = bid&7 -> one layer per XCD; wg = bid>>3), block = 256 (4 waves),
// dynLDS = 32KB. Rec-half B in 128 VGPR/lane. Critical chain per step (all L2-local):
//   poll(sc0) -> aH -> recGEMM -> cell -> stores -> vmcnt(8) -> flagL.
// inGEMM(t+1) + hnext MALL drain + flagN run AFTER flagL (off the recurrence chain).
__global__ __launch_bounds__(256, 1)
void lstm_pipeline(const f16* __restrict__ xcat, const f16* __restrict__ wlds,
                   const f16* __restrict__ wreg, const float* __restrict__ bias,
                   f16* hnext, f16* hloc, int* flagL, int* flagN,
                   float* __restrict__ rnn_out) {
  const int layer = blockIdx.x & 7, wg = blockIdx.x >> 3;
  if (layer >= 6) return;
  extern __shared__ char smem[];
  const int stack = layer/3, level = layer - stack*3;

  { // input-half weights -> LDS (swizzled image, linear copy)
    const uint4* src = (const uint4*)(wlds + (size_t)(layer*NWG + wg)*64*256);
    uint4* dst = (uint4*)smem;
    for (int i = threadIdx.x; i < 2048; i += 256) dst[i] = src[i];
  }
  const int lane = threadIdx.x & 63, wv = threadIdx.x >> 6;
  const int lc = lane & 15, akg = lane >> 4;
  const int slot16 = lc*4 + wv;                    // poll slot (producer wg' = lc, wave wv)
  const int xcp1 = ((int)__builtin_amdgcn_s_getreg((31 << 11) | 20) & 7) + 1;  // XCC_ID+1

  // rec-half B into registers (128 VGPR/lane, resident for the whole run)
  f16x8 Brec[4][8];
  {
    const f16* wr = wreg + (size_t)(layer*NWG + wg)*4*8*64*8;
    #pragma unroll
    for (int g = 0; g < 4; ++g)
      #pragma unroll
      for (int ks = 0; ks < 8; ++ks)
        Brec[g][ks] = *(const f16x8*)(wr + ((size_t)(g*8 + ks)*64 + lane)*8);
  }
  float bI, bJ, bF, bO;
  {
    const float* bb = bias + (size_t)(layer*NWG + wg)*64;
    bI = bb[0*16 + lc]; bJ = bb[1*16 + lc]; bF = bb[2*16 + lc]; bO = bb[3*16 + lc];
  }
  __syncthreads();

  int*       flL  = flagL + (size_t)layer*(TSTEPS+1)*64;
  int*       flN  = flagN + (size_t)layer*(TSTEPS+1)*64;
  const int* flNp = flagN + (size_t)(layer-1)*(TSTEPS+1)*64;
  const int* flNn = flagN + (size_t)(layer+1)*(TSTEPS+1)*64;

  const size_t aoff = (size_t)(wv*32 + lc)*256 + (size_t)akg*8;  // A frag base (row, k)

  float c_st[2][4], hmx[2][4];
  #pragma unroll
  for (int mt = 0; mt < 2; ++mt)
    #pragma unroll
    for (int r = 0; r < 4; ++r) { c_st[mt][r] = 0.f; hmx[mt][r] = -2.f; }

  f16x8 aI[2][8];
  f32x4 acc[2][4];
  int prev_ok = 0;
  bool prev_l2 = false;

#define LOAD_AI(T)                                                                    \
  do {                                                                                \
    if (level == 0) {                                                                 \
      const f16* A_ = xcat + (size_t)(stack ? (TSTEPS - (T)) : ((T)-1))*NB*256;       \
      _Pragma("unroll")                                                               \
      for (int mt = 0; mt < 2; ++mt)                                                  \
        _Pragma("unroll")                                                             \
        for (int ks = 0; ks < 8; ++ks)                                                \
          aI[mt][ks] = ld_a_p(A_ + aoff + mt*4096 + ks*32);                           \
    } else if (prev_l2) {                                                             \
      const f16* A_ = hloc + ((size_t)(layer-1)*RINGN + (size_t)((T) & 7))*HSLOT;     \
      _Pragma("unroll")                                                               \
      for (int mt = 0; mt < 2; ++mt)                                                  \
        _Pragma("unroll")                                                             \
        for (int ks = 0; ks < 8; ++ks)                                                \
          aI[mt][ks] = ld_a_l(A_ + aoff + mt*4096 + ks*32);                           \
    } else {                                                                          \
      const f16* A_ = hnext + ((size_t)(layer-1)*RINGN + (size_t)((T) & 7))*HSLOT;    \
      _Pragma("unroll")                                                               \
      for (int mt = 0; mt < 2; ++mt)                                                  \
        _Pragma("unroll")                                                             \
        for (int ks = 0; ks < 8; ++ks)                                                \
          aI[mt][ks] = ldA_coh(A_ + aoff + mt*4096 + ks*32);                          \
    }                                                                                 \
  } while (0)

#define IN_GEMM()                                                                     \
  do {                                                                                \
    _Pragma("unroll")                                                                 \
    for (int mt = 0; mt < 2; ++mt)                                                    \
      _Pragma("unroll")                                                               \
      for (int g = 0; g < 4; ++g) acc[mt][g] = (f32x4){0.f,0.f,0.f,0.f};              \
    _Pragma("unroll")                                                                 \
    for (int ks = 0; ks < 8; ++ks) {                                                  \
      const int swz = (((ks*4 + akg) ^ (lc & 7)) << 4);                               \
      f16x8 vb0 = *(const f16x8*)(smem + (0*16 + lc)*512 + swz);                      \
      f16x8 vb1 = *(const f16x8*)(smem + (1*16 + lc)*512 + swz);                      \
      f16x8 vb2 = *(const f16x8*)(smem + (2*16 + lc)*512 + swz);                      \
      f16x8 vb3 = *(const f16x8*)(smem + (3*16 + lc)*512 + swz);                      \
      _Pragma("unroll")                                                               \
      for (int mt = 0; mt < 2; ++mt) {                                                \
        acc[mt][0] = __builtin_amdgcn_mfma_f32_16x16x32_f16(aI[mt][ks], vb0, acc[mt][0],0,0,0); \
        acc[mt][1] = __builtin_amdgcn_mfma_f32_16x16x32_f16(aI[mt][ks], vb1, acc[mt][1],0,0,0); \
        acc[mt][2] = __builtin_amdgcn_mfma_f32_16x16x32_f16(aI[mt][ks], vb2, acc[mt][2],0,0,0); \
        acc[mt][3] = __builtin_amdgcn_mfma_f32_16x16x32_f16(aI[mt][ks], vb3, acc[mt][3],0,0,0); \
      }                                                                               \
    }                                                                                 \
  } while (0)

  // ---- prologue: prev lookahead, aI(1), inGEMM(1) ----
  if (level) {
    int la = 4 > TSTEPS ? TSTEPS : 4;
    int v = poll_agent(flNp + (size_t)la*64 + slot16);
    prev_l2 = __all(v == xcp1);
    prev_ok = la;
  }
  LOAD_AI(1);
  vm_wait(0);
  IN_GEMM();

  for (int t = 1; t <= TSTEPS; ++t) {
    // A. own-poll(t-1): sc0 fast path; MALL fallback only every 8th spin
    bool fast;
    {
      const int* qL = flL + (size_t)(t-1)*64 + slot16;
      const int* qN = flN + (size_t)(t-1)*64 + slot16;
      int it = 0;
      for (;;) {
        int vL = ld_flag_l(qL);
        if (__all(vL == xcp1)) { fast = true; break; }
        if ((++it & 7) == 0) {
          int vN = __hip_atomic_load(qN, __ATOMIC_RELAXED, __HIP_MEMORY_SCOPE_AGENT);
          if (__all(vN != 0)) { fast = false; break; }
        }
        __builtin_amdgcn_s_sleep(1);
      }
    }
    __builtin_amdgcn_sched_barrier(0);

    // B. issue 16 aH loads (own h_{t-1})
    f16x8 aH[2][8];
    {
      const size_t hb = ((size_t)layer*RINGN + (size_t)((t-1) & 7))*HSLOT;
      if (fast) {
        const f16* A = hloc + hb;
        #pragma unroll
        for (int mt = 0; mt < 2; ++mt)
          #pragma unroll
          for (int ks = 0; ks < 8; ++ks)
            aH[mt][ks] = ld_a_l(A + aoff + mt*4096 + ks*32);
      } else {
        const f16* A = hnext + hb;
        #pragma unroll
        for (int mt = 0; mt < 2; ++mt)
          #pragma unroll
          for (int ks = 0; ks < 8; ++ks)
            aH[mt][ks] = ldA_coh(A + aoff + mt*4096 + ks*32);
      }
    }
    __builtin_amdgcn_sched_barrier(0);

    // C. occasional cross-layer polls (overlap aH flight)
    if (level < 2 && t >= 8 && (t & 1) == 0)
      poll_agent(flNn + (size_t)(t-6)*64 + slot16);        // ring-8 backpressure
    if (level && t < TSTEPS && prev_ok < t + 1) {          // prev lookahead for aI(t+1)
      int la = (t + 4 <= TSTEPS) ? t + 4 : TSTEPS;
      int v = poll_agent(flNp + (size_t)la*64 + slot16);
      prev_l2 = __all(v == xcp1);
      prev_ok = la;
    }
    __builtin_amdgcn_sched_barrier(0);

    // D. wait aH (only outstanding VMEM), rec-half GEMM (acc += aH x Brec)
    vm_wait(0);
    #pragma unroll
    for (int ks = 0; ks < 8; ++ks)
      #pragma unroll
      for (int mt = 0; mt < 2; ++mt) {
        acc[mt][0] = __builtin_amdgcn_mfma_f32_16x16x32_f16(aH[mt][ks], Brec[0][ks], acc[mt][0],0,0,0);
        acc[mt][1] = __builtin_amdgcn_mfma_f32_16x16x32_f16(aH[mt][ks], Brec[1][ks], acc[mt][1],0,0,0);
        acc[mt][2] = __builtin_amdgcn_mfma_f32_16x16x32_f16(aH[mt][ks], Brec[2][ks], acc[mt][2],0,0,0);
        acc[mt][3] = __builtin_amdgcn_mfma_f32_16x16x32_f16(aH[mt][ks], Brec[3][ks], acc[mt][3],0,0,0);
      }
    __builtin_amdgcn_sched_barrier(0);

    // E. issue aI(t+1): FIRST into the vm queue (flies under cell + stores)
    if (t < TSTEPS) LOAD_AI(t + 1);
    __builtin_amdgcn_sched_barrier(0);

    // F. cell update (fully lane-local: 4 gates of unit wg*16+lc, 8 rows)
    short hh[2][4];
    #pragma unroll
    for (int mt = 0; mt < 2; ++mt) {
      #pragma unroll
      for (int r = 0; r < 4; ++r) {
        float zi = acc[mt][0][r] + bI;
        float zj = acc[mt][1][r] + bJ;
        float zf = acc[mt][2][r] + bF;               // forget +1 folded
        float zo = acc[mt][3][r] + bO;
        float cs = sigf(zf)*c_st[mt][r] + sigf(zi)*tanhf_(zj);
        c_st[mt][r] = cs;
        float h = sigf(zo)*tanhf_(cs);
        if (level == 2) hmx[mt][r] = fmaxf(hmx[mt][r], h);
        union { f16 h; short s; } cv; cv.h = (f16)h;
        hh[mt][r] = cv.s;
      }
    }

    // G. stores: 8 hloc (L2, plain) then 8 hnext (MALL, atomic)
    {
      const size_t ob = ((size_t)layer*RINGN + (size_t)(t & 7))*HSLOT;
      f16* hl = hloc  + ob;
      f16* hn = hnext + ob;
      #pragma unroll
      for (int mt = 0; mt < 2; ++mt)
        #pragma unroll
        for (int r = 0; r < 4; ++r) {
          int row = wv*32 + mt*16 + akg*4 + r;
          st_h_l(hl + (size_t)row*256 + wg*16 + lc, hh[mt][r]);
        }
      __builtin_amdgcn_sched_barrier(0);
      #pragma unroll
      for (int mt = 0; mt < 2; ++mt)
        #pragma unroll
        for (int r = 0; r < 4; ++r) {
          int row = wv*32 + mt*16 + akg*4 + r;
          __hip_atomic_store((short*)(hn + (size_t)row*256 + wg*16 + lc), hh[mt][r],
                             __ATOMIC_RELAXED, __HIP_MEMORY_SCOPE_AGENT);
        }
      __builtin_amdgcn_sched_barrier(0);
    }

    // H. vmcnt(8): aI(t+1)+hloc done, 8 hnext still flying -> post flagL (L2, fast path)
    vm_wait(8);
    if (lane == 0) st_flag_plain(flL + (size_t)t*64 + wg*4 + wv, xcp1);

    // I. inGEMM(t+1) while hnext drains (aI complete per vmcnt(8))
    if (t < TSTEPS) IN_GEMM();

    // J. full drain (hnext @MALL) -> post flagN (inter-layer/fallback)
    vm_wait(0);
    if (lane == 0)
      __hip_atomic_store(flN + (size_t)t*64 + wg*4 + wv, xcp1,
                         __ATOMIC_RELAXED, __HIP_MEMORY_SCOPE_AGENT);
  }
#undef LOAD_AI
#undef IN_GEMM

  if (level == 2) {
    #pragma unroll
    for (int mt = 0; mt < 2; ++mt)
      #pragma unroll
      for (int r = 0; r < 4; ++r)
        rnn_out[(size_t)(wv*32 + mt*16 + akg*4 + r)*512 + stack*256 + wg*16 + lc]
            = hmx[mt][r];
  }
}

// ---------------- epilogue: elu(rnn@W1+b1)@W2+b2 -> sigmoid ----------------
__global__ __launch_bounds__(256)
void dense_kernel(const float* __restrict__ rnn, const float* __restrict__ W1,
                  const float* __restrict__ b1, const float* __restrict__ W2,
                  const float* __restrict__ b2, float* __restrict__ out) {
  __shared__ float h1[16][64];
  int r0 = blockIdx.x*16;
  int c = threadIdx.x & 63, rr = threadIdx.x >> 6;
  #pragma unroll
  for (int m = 0; m < 4; ++m) {
    int rl = rr*4 + m;
    const float* rp = rnn + (size_t)(r0 + rl)*512;
    float s = b1[c];
    for (int k = 0; k < 512; ++k) s = fmaf(rp[k], W1[(size_t)k*64 + c], s);
    h1[rl][c] = (s > 0.f) ? s : (__expf(s) - 1.f);
  }
  __syncthreads();
  if (threadIdx.x < 96) {
    int rl = threadIdx.x/6, cc = threadIdx.x - rl*6;
    float s = b2[cc];
    #pragma unroll
    for (int k = 0; k < 64; ++k) s = fmaf(h1[rl][k], W2[k*6 + cc], s);
    out[(size_t)(r0 + rl)*6 + cc] = 1.f/(1.f + __expf(-s));
  }
}

// ---------------- launch ----------------
extern "C" void kernel_launch(void* const* d_in, const int* in_sizes, int n_in,
                              void* d_out, int out_size, void* d_ws, size_t ws_size,
                              hipStream_t stream) {
  if (ws_size < WS_NEED) return;  // clean failure instead of corruption
  const int*   words = (const int*)d_in[0];
  const int*   caps  = (const int*)d_in[1];
  const float* emb   = (const float*)d_in[2];
  const float* capt  = (const float*)d_in[3];
  char* ws = (char*)d_ws;
  f16*   xcat  = (f16*)  (ws + OFF_XCAT);
  f16*   wlds  = (f16*)  (ws + OFF_WLDS);
  f16*   wreg  = (f16*)  (ws + OFF_WREG);
  float* bias  = (float*)(ws + OFF_BIAS);
  f16*   hnext = (f16*)  (ws + OFF_HNEXT);
  f16*   hloc  = (f16*)  (ws + OFF_HLOC);
  int*   flagL = (int*)  (ws + OFF_FLAGL);
  int*   flagN = (int*)  (ws + OFF_FLAGN);
  float* rnn   = (float*)(ws + OFF_RNN);

  embed_kernel<<<TSTEPS*NB, 256, 0, stream>>>(words, caps, emb, capt, xcat);
  pack_kernel<<<6144 + 384, 256, 0, stream>>>(
      (const float*)d_in[4],  (const float*)d_in[5],  (const float*)d_in[6],  (const float*)d_in[7],
      (const float*)d_in[8],  (const float*)d_in[9],  (const float*)d_in[10], (const float*)d_in[11],
      (const float*)d_in[12], (const float*)d_in[13], (const float*)d_in[14], (const float*)d_in[15],
      wlds, wreg, bias);
  init_kernel<<<768, 256, 0, stream>>>(flagL, flagN, hnext);
  lstm_pipeline<<<128, 256, 32768, stream>>>(xcat, wlds, wreg, bias, hnext, hloc,
                                             flagL, flagN, rnn);
  dense_kernel<<<8, 256, 0, stream>>>(rnn, (const float*)d_in[16], (const float*)d_in[17],
                                      (const float*)d_in[18], (const float*)d_in[19], (float*)d_out);
}

// Round 10
// 4637.354 us; speedup vs baseline: 1.0860x; 1.0860x over previous
//
#include <hip/hip_runtime.h>
#include <stdint.h>

#define TSTEPS 500
#define NB 128
#define NH 256
#define RINGN 8

typedef _Float16 f16;
typedef _Float16 f16x8 __attribute__((ext_vector_type(8)));
typedef float f32x4 __attribute__((ext_vector_type(4)));
typedef unsigned long long u64;
typedef unsigned int u32;

// ---------------- workspace layout ----------------
static constexpr size_t HSLOT = (size_t)NB*NH;                      // 32768 f16 per (layer,t)
static constexpr size_t SZ_XCAT  = (size_t)TSTEPS*NB*256*2;         // 32.77 MB
static constexpr size_t SZ_WLDS  = (size_t)6*4*256*256*2;           // 3.15 MB input-half LDS image
static constexpr size_t SZ_WREG  = (size_t)6*4*4*4*8*64*8*2;        // 3.15 MB rec-half reg image
static constexpr size_t SZ_BIAS  = (size_t)6*4*256*4;
static constexpr size_t SZ_HNEXT = (size_t)6*RINGN*HSLOT*2;         // MALL-coherent ring
static constexpr size_t SZ_HLOC  = (size_t)6*RINGN*HSLOT*2;         // XCD-local L2 ring
static constexpr size_t SZ_FLAG  = (size_t)6*(TSTEPS+1)*16*4;       // per-WG flags (4rg x 4ug)
static constexpr size_t SZ_RNN   = (size_t)NB*512*4;
static constexpr size_t OFF_XCAT  = 0;
static constexpr size_t OFF_WLDS  = OFF_XCAT + SZ_XCAT;
static constexpr size_t OFF_WREG  = OFF_WLDS + SZ_WLDS;
static constexpr size_t OFF_BIAS  = OFF_WREG + SZ_WREG;
static constexpr size_t OFF_HNEXT = OFF_BIAS + SZ_BIAS;
static constexpr size_t OFF_HLOC  = OFF_HNEXT + SZ_HNEXT;
static constexpr size_t OFF_FLAGL = OFF_HLOC + SZ_HLOC;
static constexpr size_t OFF_FLAGN = OFF_FLAGL + SZ_FLAG;
static constexpr size_t OFF_RNN   = (OFF_FLAGN + SZ_FLAG + 255) & ~(size_t)255;
static constexpr size_t WS_NEED   = OFF_RNN + SZ_RNN;               // ~46 MB

// ---------------- prep: embed + concat + pad, cast f16 ----------------
__global__ void embed_kernel(const int* __restrict__ words,
                             const int* __restrict__ caps,
                             const float* __restrict__ emb,
                             const float* __restrict__ capt,
                             f16* __restrict__ xcat) {
  int t = blockIdx.x >> 7, b = blockIdx.x & 127, k = threadIdx.x;
  int w  = words[b*TSTEPS + t];
  int cp = caps [b*TSTEPS + t];
  float v = 0.f;
  if (k < 200)      v = emb[(size_t)w*200 + k];
  else if (k < 203) v = capt[cp*3 + (k-200)];
  xcat[((size_t)t*NB + b)*256 + k] = (f16)v;
}

// ---------------- prep: pack weights ----------------
// part1 (bid<6144): input-half LDS image per (layer,ug): n=0..255 (g=n>>6,u=n&63) ->
//   col g*256+ug*64+u; k 0..255 (level0: rows 0..202 + pad); per-column 16B XOR swizzle.
// part2: rec-half reg image per (layer,ug,wv,g): lane -> col g*256+ug*64+wv*16+(lane&15),
//   k = ks*32+(lane>>4)*8+j, rec rows base 203/256.
__global__ void pack_kernel(const float* __restrict__ Wf0, const float* __restrict__ bf0,
                            const float* __restrict__ Wf1, const float* __restrict__ bf1,
                            const float* __restrict__ Wf2, const float* __restrict__ bf2,
                            const float* __restrict__ Wb0, const float* __restrict__ bb0,
                            const float* __restrict__ Wb1, const float* __restrict__ bb1,
                            const float* __restrict__ Wb2, const float* __restrict__ bb2,
                            f16* __restrict__ wlds, f16* __restrict__ wreg,
                            float* __restrict__ bias) {
  int bid = blockIdx.x;
  int layer;
  const float* W; const float* bb;
  int part1 = (bid < 6144);
  if (part1) layer = bid >> 10;
  else       layer = (bid - 6144) >> 6;
  switch (layer) {
    case 0: W = Wf0; bb = bf0; break;
    case 1: W = Wf1; bb = bf1; break;
    case 2: W = Wf2; bb = bf2; break;
    case 3: W = Wb0; bb = bb0; break;
    case 4: W = Wb1; bb = bb1; break;
    default: W = Wb2; bb = bb2; break;
  }
  int level = layer % 3;
  if (part1) {
    int ug = (bid >> 8) & 3;
    int n = bid & 255;
    int g = n >> 6, u = n & 63;
    int col = g*256 + ug*64 + u;
    if (threadIdx.x == 0)
      bias[(size_t)(layer*4 + ug)*256 + n] = bb[col] + (g == 2 ? 1.f : 0.f);
    int k = threadIdx.x;                                    // 0..255
    int row = (level == 0) ? ((k < 203) ? k : -1) : k;
    float v = (row < 0) ? 0.f : W[(size_t)row*1024 + col];
    int idx = (((k >> 3) ^ (n & 7)) << 3) | (k & 7);
    wlds[((size_t)(layer*4 + ug)*256 + n)*256 + idx] = (f16)v;
  } else {
    int r2 = (bid - 6144) & 63;
    int ug = r2 >> 4, wv = (r2 >> 2) & 3, g = r2 & 3;
    int lane = threadIdx.x & 63;
    int col = g*256 + ug*64 + wv*16 + (lane & 15);
    int rbase = (level == 0) ? 203 : 256;
    for (int ks = threadIdx.x >> 6; ks < 8; ks += 4) {
      size_t base = ((((size_t)(layer*4 + ug)*4 + wv)*4 + g)*8 + ks)*512 + (size_t)lane*8;
      #pragma unroll
      for (int j = 0; j < 8; ++j) {
        int k = ks*32 + ((lane >> 4)*8) + j;
        wreg[base + j] = (f16)W[(size_t)(rbase + k)*1024 + col];
      }
    }
  }
}

// ---------------- prep: flags + hnext ring slot0 = h_0 = 0 ----------------
__global__ void init_kernel(int* __restrict__ flagL, int* __restrict__ flagN,
                            f16* __restrict__ hnext) {
  int i = blockIdx.x*256 + threadIdx.x;
  if (i < 6*(TSTEPS+1)*16) {
    int t = (i >> 4) % (TSTEPS+1);
    flagL[i] = 0;
    flagN[i] = (t == 0) ? 9 : 0;                  // 9 never matches xcc+1 in [1,8]
  }
  if (i < 98304) {                                // hnext slot 0 = zeros per layer
    int l = i >> 14, e = i & 16383;
    ((u32*)(hnext + (size_t)l*RINGN*HSLOT))[e] = 0u;
  }
}

// ---------------- helpers ----------------
__device__ __forceinline__ int poll_agent(const int* q) {
  int v;
  for (;;) {
    v = __hip_atomic_load(q, __ATOMIC_RELAXED, __HIP_MEMORY_SCOPE_AGENT);
    if (__all(v != 0)) break;
    __builtin_amdgcn_s_sleep(1);
  }
  return v;
}
__device__ __forceinline__ int ld_flag_l(const int* p) {       // sc0: L1-bypass L2 read
  int v;
  asm volatile("global_load_dword %0, %1, off sc0\n\ts_waitcnt vmcnt(0)"
               : "=v"(v) : "v"(p) : "memory");
  return v;
}
__device__ __forceinline__ f16x8 ld_a_l(const f16* p) {        // 16B same-XCD L2 load
  f16x8 v;
  asm volatile("global_load_dwordx4 %0, %1, off sc0" : "=v"(v) : "v"(p));
  return v;
}
__device__ __forceinline__ f16x8 ld_a_p(const f16* p) {        // 16B plain cached load
  f16x8 v;
  asm volatile("global_load_dwordx4 %0, %1, off" : "=v"(v) : "v"(p));
  return v;
}
__device__ __forceinline__ f16x8 ldA_coh(const f16* p) {       // cross-XCD via MALL (proven)
  union { u64 q[2]; f16x8 v; } u;
  u.q[0] = __hip_atomic_load((const u64*)p,     __ATOMIC_RELAXED, __HIP_MEMORY_SCOPE_AGENT);
  u.q[1] = __hip_atomic_load((const u64*)p + 1, __ATOMIC_RELAXED, __HIP_MEMORY_SCOPE_AGENT);
  return u.v;
}
__device__ __forceinline__ void st_h_l(f16* p, short s) {      // plain store -> own-XCD L2
  asm volatile("global_store_short %0, %1, off" :: "v"(p), "v"((int)s) : "memory");
}
__device__ __forceinline__ void st_flag_plain(int* p, int v) {
  asm volatile("global_store_dword %0, %1, off" :: "v"(p), "v"(v) : "memory");
}
__device__ __forceinline__ void vm_wait(int n) {
  if (n == 0)      asm volatile("s_waitcnt vmcnt(0)" ::: "memory");
  else if (n == 8) asm volatile("s_waitcnt vmcnt(8)" ::: "memory");
  __builtin_amdgcn_sched_barrier(0);
}
__device__ __forceinline__ float sigf(float x) {
  return __builtin_amdgcn_rcpf(1.f + __expf(-x));
}
__device__ __forceinline__ float tanhf_(float x) {
  float e = __expf(-2.f*fabsf(x));
  float r = (1.f - e) * __builtin_amdgcn_rcpf(1.f + e);
  return x < 0.f ? -r : r;
}

// grid = 128 (layer = bid&7 -> one layer per XCD; sub = bid>>3: rg = sub>>2, ug = sub&3),
// block = 256 (4 waves), dynLDS = 128KB (input-half, 256 cols). BATCH-SPLIT SYNC TOPOLOGY:
// WG owns 32 batch rows (rg) x 64 units (ug); recurrence for row-group rg needs only the 4
// ug-WGs of the SAME rg -> per-step fan-in 4 (was 16), and the 4 rg pipelines (across all 6
// layers) are fully independent. Per-WG flag posted after __syncthreads. Dual-flag protocol
// (flagL sc0-L2 fast / flagN MALL fallback) unchanged from R6-R9 (liveness-proven).
__global__ __launch_bounds__(256, 1)
void lstm_pipeline(const f16* __restrict__ xcat, const f16* __restrict__ wlds,
                   const f16* __restrict__ wreg, const float* __restrict__ bias,
                   f16* hnext, f16* hloc, int* flagL, int* flagN,
                   float* __restrict__ rnn_out) {
  const int layer = blockIdx.x & 7, sub = blockIdx.x >> 3;
  if (layer >= 6) return;
  const int rg = sub >> 2, ug = sub & 3;
  extern __shared__ char smem[];
  const int stack = layer/3, level = layer - stack*3;

  { // input-half weights -> LDS (swizzled image, 128KB linear copy)
    const uint4* src = (const uint4*)(wlds + (size_t)(layer*4 + ug)*256*256);
    uint4* dst = (uint4*)smem;
    for (int i = threadIdx.x; i < 8192; i += 256) dst[i] = src[i];
  }
  const int lane = threadIdx.x & 63, wv = threadIdx.x >> 6;
  const int lc = lane & 15, akg = lane >> 4;
  const int slot4 = rg*4 + (lane & 3);             // replicated poll slot (4 ug producers)
  const int xcp1 = ((int)__builtin_amdgcn_s_getreg((31 << 11) | 20) & 7) + 1;  // XCC_ID+1

  // rec-half B into registers (128 VGPR/lane, resident for the whole run)
  f16x8 Brec[4][8];
  {
    const f16* wr = wreg + ((size_t)(layer*4 + ug)*4 + wv)*4*8*512;
    #pragma unroll
    for (int g = 0; g < 4; ++g)
      #pragma unroll
      for (int ks = 0; ks < 8; ++ks)
        Brec[g][ks] = *(const f16x8*)(wr + ((size_t)(g*8 + ks)*64 + lane)*8);
  }
  float bI, bJ, bF, bO;
  {
    const float* bb = bias + (size_t)(layer*4 + ug)*256 + wv*16 + lc;
    bI = bb[0*64]; bJ = bb[1*64]; bF = bb[2*64]; bO = bb[3*64];
  }
  __syncthreads();

  const size_t FL = (size_t)(TSTEPS+1)*16;
  int*       flL  = flagL + (size_t)layer*FL;
  int*       flN  = flagN + (size_t)layer*FL;
  const int* flNp = flagN + (size_t)(layer-1)*FL;
  const int* flNn = flagN + (size_t)(layer+1)*FL;

  const size_t aoff = (size_t)(rg*32 + lc)*256 + (size_t)akg*8;  // A frag base (+mt*4096)
  const int ucol = ug*64 + wv*16 + lc;                           // this lane's unit column

  float c_st[2][4], hmx[2][4];
  #pragma unroll
  for (int mt = 0; mt < 2; ++mt)
    #pragma unroll
    for (int r = 0; r < 4; ++r) { c_st[mt][r] = 0.f; hmx[mt][r] = -2.f; }

  f16x8 aI[2][8];
  f32x4 acc[2][4];
  int prev_ok = 0;
  bool prev_l2 = false;

#define LOAD_AI(T)                                                                    \
  do {                                                                                \
    if (level == 0) {                                                                 \
      const f16* A_ = xcat + (size_t)(stack ? (TSTEPS - (T)) : ((T)-1))*NB*256;       \
      _Pragma("unroll")                                                               \
      for (int mt = 0; mt < 2; ++mt)                                                  \
        _Pragma("unroll")                                                             \
        for (int ks = 0; ks < 8; ++ks)                                                \
          aI[mt][ks] = ld_a_p(A_ + aoff + mt*4096 + ks*32);                           \
    } else if (prev_l2) {                                                             \
      const f16* A_ = hloc + ((size_t)(layer-1)*RINGN + (size_t)((T) & 7))*HSLOT;     \
      _Pragma("unroll")                                                               \
      for (int mt = 0; mt < 2; ++mt)                                                  \
        _Pragma("unroll")                                                             \
        for (int ks = 0; ks < 8; ++ks)                                                \
          aI[mt][ks] = ld_a_l(A_ + aoff + mt*4096 + ks*32);                           \
    } else {                                                                          \
      const f16* A_ = hnext + ((size_t)(layer-1)*RINGN + (size_t)((T) & 7))*HSLOT;    \
      _Pragma("unroll")                                                               \
      for (int mt = 0; mt < 2; ++mt)                                                  \
        _Pragma("unroll")                                                             \
        for (int ks = 0; ks < 8; ++ks)                                                \
          aI[mt][ks] = ldA_coh(A_ + aoff + mt*4096 + ks*32);                          \
    }                                                                                 \
  } while (0)

#define IN_GEMM()                                                                     \
  do {                                                                                \
    _Pragma("unroll")                                                                 \
    for (int mt = 0; mt < 2; ++mt)                                                    \
      _Pragma("unroll")                                                               \
      for (int g = 0; g < 4; ++g) acc[mt][g] = (f32x4){0.f,0.f,0.f,0.f};              \
    _Pragma("unroll")                                                                 \
    for (int ks = 0; ks < 8; ++ks) {                                                  \
      const int swz = (((ks*4 + akg) ^ (lc & 7)) << 4);                               \
      f16x8 vb0 = *(const f16x8*)(smem + (0*64 + wv*16 + lc)*512 + swz);              \
      f16x8 vb1 = *(const f16x8*)(smem + (1*64 + wv*16 + lc)*512 + swz);              \
      f16x8 vb2 = *(const f16x8*)(smem + (2*64 + wv*16 + lc)*512 + swz);              \
      f16x8 vb3 = *(const f16x8*)(smem + (3*64 + wv*16 + lc)*512 + swz);              \
      _Pragma("unroll")                                                               \
      for (int mt = 0; mt < 2; ++mt) {                                                \
        acc[mt][0] = __builtin_amdgcn_mfma_f32_16x16x32_f16(aI[mt][ks], vb0, acc[mt][0],0,0,0); \
        acc[mt][1] = __builtin_amdgcn_mfma_f32_16x16x32_f16(aI[mt][ks], vb1, acc[mt][1],0,0,0); \
        acc[mt][2] = __builtin_amdgcn_mfma_f32_16x16x32_f16(aI[mt][ks], vb2, acc[mt][2],0,0,0); \
        acc[mt][3] = __builtin_amdgcn_mfma_f32_16x16x32_f16(aI[mt][ks], vb3, acc[mt][3],0,0,0); \
      }                                                                               \
    }                                                                                 \
  } while (0)

  // ---- prologue: prev lookahead, aI(1), inGEMM(1) ----
  if (level) {
    int la = 4 > TSTEPS ? TSTEPS : 4;
    int v = poll_agent(flNp + (size_t)la*16 + slot4);
    prev_l2 = __all(v == xcp1);
    prev_ok = la;
  }
  LOAD_AI(1);
  vm_wait(0);
  IN_GEMM();

  for (int t = 1; t <= TSTEPS; ++t) {
    // A. own-rg poll(t-1): 4 ug flags; sc0 fast path, MALL fallback every 4th spin
    bool fast;
    {
      const int* qL = flL + (size_t)(t-1)*16 + slot4;
      const int* qN = flN + (size_t)(t-1)*16 + slot4;
      int it = 0;
      for (;;) {
        int vL = ld_flag_l(qL);
        if (__all(vL == xcp1)) { fast = true; break; }
        if ((++it & 3) == 0) {
          int vN = __hip_atomic_load(qN, __ATOMIC_RELAXED, __HIP_MEMORY_SCOPE_AGENT);
          if (__all(vN != 0)) { fast = false; break; }
        }
        __builtin_amdgcn_s_sleep(1);
      }
    }
    __builtin_amdgcn_sched_barrier(0);

    // B. issue 16 aH loads (own rg rows x all 256 units of h_{t-1})
    f16x8 aH[2][8];
    {
      const size_t hb = ((size_t)layer*RINGN + (size_t)((t-1) & 7))*HSLOT;
      if (fast) {
        const f16* A = hloc + hb;
        #pragma unroll
        for (int mt = 0; mt < 2; ++mt)
          #pragma unroll
          for (int ks = 0; ks < 8; ++ks)
            aH[mt][ks] = ld_a_l(A + aoff + mt*4096 + ks*32);
      } else {
        const f16* A = hnext + hb;
        #pragma unroll
        for (int mt = 0; mt < 2; ++mt)
          #pragma unroll
          for (int ks = 0; ks < 8; ++ks)
            aH[mt][ks] = ldA_coh(A + aoff + mt*4096 + ks*32);
      }
    }
    __builtin_amdgcn_sched_barrier(0);

    // C. amortized rg-local cross-layer polls (overlap aH flight; fan-in 4)
    if (level < 2 && t >= 8 && (t & 1) == 0)
      poll_agent(flNn + (size_t)(t-6)*16 + slot4);         // ring-8 backpressure
    if (level && t < TSTEPS && prev_ok < t + 1) {          // prev lookahead for aI(t+1)
      int la = (t + 4 <= TSTEPS) ? t + 4 : TSTEPS;
      int v = poll_agent(flNp + (size_t)la*16 + slot4);
      prev_l2 = __all(v == xcp1);
      prev_ok = la;
    }
    __builtin_amdgcn_sched_barrier(0);

    // D. wait aH (only outstanding VMEM), rec-half GEMM (acc += aH x Brec, zero LDS)
    vm_wait(0);
    #pragma unroll
    for (int ks = 0; ks < 8; ++ks)
      #pragma unroll
      for (int mt = 0; mt < 2; ++mt) {
        acc[mt][0] = __builtin_amdgcn_mfma_f32_16x16x32_f16(aH[mt][ks], Brec[0][ks], acc[mt][0],0,0,0);
        acc[mt][1] = __builtin_amdgcn_mfma_f32_16x16x32_f16(aH[mt][ks], Brec[1][ks], acc[mt][1],0,0,0);
        acc[mt][2] = __builtin_amdgcn_mfma_f32_16x16x32_f16(aH[mt][ks], Brec[2][ks], acc[mt][2],0,0,0);
        acc[mt][3] = __builtin_amdgcn_mfma_f32_16x16x32_f16(aH[mt][ks], Brec[3][ks], acc[mt][3],0,0,0);
      }
    __builtin_amdgcn_sched_barrier(0);

    // E. issue aI(t+1): FIRST into the vm queue (flies under cell + stores)
    if (t < TSTEPS) LOAD_AI(t + 1);
    __builtin_amdgcn_sched_barrier(0);

    // F. cell update (lane-local: 4 gates of unit ucol, 8 rows)
    short hh[2][4];
    #pragma unroll
    for (int mt = 0; mt < 2; ++mt) {
      #pragma unroll
      for (int r = 0; r < 4; ++r) {
        float zi = acc[mt][0][r] + bI;
        float zj = acc[mt][1][r] + bJ;
        float zf = acc[mt][2][r] + bF;               // forget +1 folded
        float zo = acc[mt][3][r] + bO;
        float cs = sigf(zf)*c_st[mt][r] + sigf(zi)*tanhf_(zj);
        c_st[mt][r] = cs;
        float h = sigf(zo)*tanhf_(cs);
        if (level == 2) hmx[mt][r] = fmaxf(hmx[mt][r], h);
        union { f16 h; short s; } cv; cv.h = (f16)h;
        hh[mt][r] = cv.s;
      }
    }

    // G. stores: 8 hloc (L2, plain) then 8 hnext (MALL, atomic)
    {
      const size_t ob = ((size_t)layer*RINGN + (size_t)(t & 7))*HSLOT;
      f16* hl = hloc  + ob;
      f16* hn = hnext + ob;
      #pragma unroll
      for (int mt = 0; mt < 2; ++mt)
        #pragma unroll
        for (int r = 0; r < 4; ++r) {
          int row = rg*32 + mt*16 + akg*4 + r;
          st_h_l(hl + (size_t)row*256 + ucol, hh[mt][r]);
        }
      __builtin_amdgcn_sched_barrier(0);
      #pragma unroll
      for (int mt = 0; mt < 2; ++mt)
        #pragma unroll
        for (int r = 0; r < 4; ++r) {
          int row = rg*32 + mt*16 + akg*4 + r;
          __hip_atomic_store((short*)(hn + (size_t)row*256 + ucol), hh[mt][r],
                             __ATOMIC_RELAXED, __HIP_MEMORY_SCOPE_AGENT);
        }
      __builtin_amdgcn_sched_barrier(0);
    }

    // H. vmcnt(8): aI(t+1)+hloc done (hnext still flying); WG barrier; ONE flagL per WG
    vm_wait(8);
    __syncthreads();
    if (threadIdx.x == 0) st_flag_plain(flL + (size_t)t*16 + rg*4 + ug, xcp1);

    // I. inGEMM(t+1) while hnext drains (aI complete per vmcnt(8))
    if (t < TSTEPS) IN_GEMM();

    // J. full drain (hnext @MALL); WG barrier; ONE flagN per WG
    vm_wait(0);
    __syncthreads();
    if (threadIdx.x == 0)
      __hip_atomic_store(flN + (size_t)t*16 + rg*4 + ug, xcp1,
                         __ATOMIC_RELAXED, __HIP_MEMORY_SCOPE_AGENT);
  }
#undef LOAD_AI
#undef IN_GEMM

  if (level == 2) {
    #pragma unroll
    for (int mt = 0; mt < 2; ++mt)
      #pragma unroll
      for (int r = 0; r < 4; ++r)
        rnn_out[(size_t)(rg*32 + mt*16 + akg*4 + r)*512 + stack*256 + ucol] = hmx[mt][r];
  }
}

// ---------------- epilogue: elu(rnn@W1+b1)@W2+b2 -> sigmoid ----------------
__global__ __launch_bounds__(256)
void dense_kernel(const float* __restrict__ rnn, const float* __restrict__ W1,
                  const float* __restrict__ b1, const float* __restrict__ W2,
                  const float* __restrict__ b2, float* __restrict__ out) {
  __shared__ float h1[16][64];
  int r0 = blockIdx.x*16;
  int c = threadIdx.x & 63, rr = threadIdx.x >> 6;
  #pragma unroll
  for (int m = 0; m < 4; ++m) {
    int rl = rr*4 + m;
    const float* rp = rnn + (size_t)(r0 + rl)*512;
    float s = b1[c];
    for (int k = 0; k < 512; ++k) s = fmaf(rp[k], W1[(size_t)k*64 + c], s);
    h1[rl][c] = (s > 0.f) ? s : (__expf(s) - 1.f);
  }
  __syncthreads();
  if (threadIdx.x < 96) {
    int rl = threadIdx.x/6, cc = threadIdx.x - rl*6;
    float s = b2[cc];
    #pragma unroll
    for (int k = 0; k < 64; ++k) s = fmaf(h1[rl][k], W2[k*6 + cc], s);
    out[(size_t)(r0 + rl)*6 + cc] = 1.f/(1.f + __expf(-s));
  }
}

// ---------------- launch ----------------
extern "C" void kernel_launch(void* const* d_in, const int* in_sizes, int n_in,
                              void* d_out, int out_size, void* d_ws, size_t ws_size,
                              hipStream_t stream) {
  if (ws_size < WS_NEED) return;  // clean failure instead of corruption
  const int*   words = (const int*)d_in[0];
  const int*   caps  = (const int*)d_in[1];
  const float* emb   = (const float*)d_in[2];
  const float* capt  = (const float*)d_in[3];
  char* ws = (char*)d_ws;
  f16*   xcat  = (f16*)  (ws + OFF_XCAT);
  f16*   wlds  = (f16*)  (ws + OFF_WLDS);
  f16*   wreg  = (f16*)  (ws + OFF_WREG);
  float* bias  = (float*)(ws + OFF_BIAS);
  f16*   hnext = (f16*)  (ws + OFF_HNEXT);
  f16*   hloc  = (f16*)  (ws + OFF_HLOC);
  int*   flagL = (int*)  (ws + OFF_FLAGL);
  int*   flagN = (int*)  (ws + OFF_FLAGN);
  float* rnn   = (float*)(ws + OFF_RNN);

  embed_kernel<<<TSTEPS*NB, 256, 0, stream>>>(words, caps, emb, capt, xcat);
  pack_kernel<<<6144 + 384, 256, 0, stream>>>(
      (const float*)d_in[4],  (const float*)d_in[5],  (const float*)d_in[6],  (const float*)d_in[7],
      (const float*)d_in[8],  (const float*)d_in[9],  (const float*)d_in[10], (const float*)d_in[11],
      (const float*)d_in[12], (const float*)d_in[13], (const float*)d_in[14], (const float*)d_in[15],
      wlds, wreg, bias);
  init_kernel<<<768, 256, 0, stream>>>(flagL, flagN, hnext);
  lstm_pipeline<<<128, 256, 131072, stream>>>(xcat, wlds, wreg, bias, hnext, hloc,
                                              flagL, flagN, rnn);
  dense_kernel<<<8, 256, 0, stream>>>(rnn, (const float*)d_in[16], (const float*)d_in[17],
                                      (const float*)d_in[18], (const float*)d_in[19], (float*)d_out);
}

// Round 11
// 3888.839 us; speedup vs baseline: 1.2950x; 1.1925x over previous
//
#include <hip/hip_runtime.h>
#include <stdint.h>

#define TSTEPS 500
#define NB 128
#define NH 256
#define RINGN 8

typedef _Float16 f16;
typedef _Float16 f16x8 __attribute__((ext_vector_type(8)));
typedef float f32x4 __attribute__((ext_vector_type(4)));
typedef unsigned long long u64;
typedef unsigned int u32;

// ---------------- workspace layout ----------------
static constexpr size_t HSLOT = (size_t)NB*NH;                      // 32768 f16 per (layer,t)
static constexpr size_t SZ_XCAT  = (size_t)TSTEPS*NB*256*2;         // 32.77 MB
static constexpr size_t SZ_WLDS  = (size_t)6*4*256*256*2;           // 3.15 MB input-half LDS image
static constexpr size_t SZ_WREG  = (size_t)6*4*4*4*8*64*8*2;        // 3.15 MB rec-half reg image
static constexpr size_t SZ_BIAS  = (size_t)6*4*256*4;
static constexpr size_t SZ_HNEXT = (size_t)6*RINGN*HSLOT*2;         // MALL-coherent ring
static constexpr size_t SZ_HLOC  = (size_t)6*RINGN*HSLOT*2;         // XCD-local L2 ring
static constexpr size_t SZ_FLAG  = (size_t)6*(TSTEPS+1)*16*4;       // per-WG flags (4rg x 4ug)
static constexpr size_t SZ_DONE  = 256;
static constexpr size_t SZ_RNN   = (size_t)NB*512*4;
static constexpr size_t OFF_XCAT  = 0;
static constexpr size_t OFF_WLDS  = OFF_XCAT + SZ_XCAT;
static constexpr size_t OFF_WREG  = OFF_WLDS + SZ_WLDS;
static constexpr size_t OFF_BIAS  = OFF_WREG + SZ_WREG;
static constexpr size_t OFF_HNEXT = OFF_BIAS + SZ_BIAS;
static constexpr size_t OFF_HLOC  = OFF_HNEXT + SZ_HNEXT;
static constexpr size_t OFF_FLAGL = OFF_HLOC + SZ_HLOC;
static constexpr size_t OFF_FLAGN = OFF_FLAGL + SZ_FLAG;
static constexpr size_t OFF_DONE  = OFF_FLAGN + SZ_FLAG;
static constexpr size_t OFF_RNN   = (OFF_DONE + SZ_DONE + 255) & ~(size_t)255;
static constexpr size_t WS_NEED   = OFF_RNN + SZ_RNN;               // ~46 MB (proven budget)

// ---------------- prep: embed + concat + pad, cast f16 ----------------
__global__ void embed_kernel(const int* __restrict__ words,
                             const int* __restrict__ caps,
                             const float* __restrict__ emb,
                             const float* __restrict__ capt,
                             f16* __restrict__ xcat) {
  int t = blockIdx.x >> 7, b = blockIdx.x & 127, k = threadIdx.x;
  int w  = words[b*TSTEPS + t];
  int cp = caps [b*TSTEPS + t];
  float v = 0.f;
  if (k < 200)      v = emb[(size_t)w*200 + k];
  else if (k < 203) v = capt[cp*3 + (k-200)];
  xcat[((size_t)t*NB + b)*256 + k] = (f16)v;
}

// ---------------- prep: pack weights (R10-proven) ----------------
__global__ void pack_kernel(const float* __restrict__ Wf0, const float* __restrict__ bf0,
                            const float* __restrict__ Wf1, const float* __restrict__ bf1,
                            const float* __restrict__ Wf2, const float* __restrict__ bf2,
                            const float* __restrict__ Wb0, const float* __restrict__ bb0,
                            const float* __restrict__ Wb1, const float* __restrict__ bb1,
                            const float* __restrict__ Wb2, const float* __restrict__ bb2,
                            f16* __restrict__ wlds, f16* __restrict__ wreg,
                            float* __restrict__ bias) {
  int bid = blockIdx.x;
  int layer;
  const float* W; const float* bb;
  int part1 = (bid < 6144);
  if (part1) layer = bid >> 10;
  else       layer = (bid - 6144) >> 6;
  switch (layer) {
    case 0: W = Wf0; bb = bf0; break;
    case 1: W = Wf1; bb = bf1; break;
    case 2: W = Wf2; bb = bf2; break;
    case 3: W = Wb0; bb = bb0; break;
    case 4: W = Wb1; bb = bb1; break;
    default: W = Wb2; bb = bb2; break;
  }
  int level = layer % 3;
  if (part1) {
    int ug = (bid >> 8) & 3;
    int n = bid & 255;
    int g = n >> 6, u = n & 63;
    int col = g*256 + ug*64 + u;
    if (threadIdx.x == 0)
      bias[(size_t)(layer*4 + ug)*256 + n] = bb[col] + (g == 2 ? 1.f : 0.f);
    int k = threadIdx.x;                                    // 0..255
    int row = (level == 0) ? ((k < 203) ? k : -1) : k;
    float v = (row < 0) ? 0.f : W[(size_t)row*1024 + col];
    int idx = (((k >> 3) ^ (n & 7)) << 3) | (k & 7);
    wlds[((size_t)(layer*4 + ug)*256 + n)*256 + idx] = (f16)v;
  } else {
    int r2 = (bid - 6144) & 63;
    int ug = r2 >> 4, wv = (r2 >> 2) & 3, g = r2 & 3;
    int lane = threadIdx.x & 63;
    int col = g*256 + ug*64 + wv*16 + (lane & 15);
    int rbase = (level == 0) ? 203 : 256;
    for (int ks = threadIdx.x >> 6; ks < 8; ks += 4) {
      size_t base = ((((size_t)(layer*4 + ug)*4 + wv)*4 + g)*8 + ks)*512 + (size_t)lane*8;
      #pragma unroll
      for (int j = 0; j < 8; ++j) {
        int k = ks*32 + ((lane >> 4)*8) + j;
        wreg[base + j] = (f16)W[(size_t)(rbase + k)*1024 + col];
      }
    }
  }
}

// ---------------- prep: flags + done + hnext ring slot0 = h_0 = 0 ----------------
__global__ void init_kernel(int* __restrict__ flagL, int* __restrict__ flagN,
                            f16* __restrict__ hnext, int* __restrict__ done) {
  int i = blockIdx.x*256 + threadIdx.x;
  if (i < 6*(TSTEPS+1)*16) {
    int t = (i >> 4) % (TSTEPS+1);
    flagL[i] = 0;
    flagN[i] = (t == 0) ? 9 : 0;                  // 9 never matches xcc+1 in [1,8]
  }
  if (i < 98304) {                                // hnext slot 0 = zeros per layer
    int l = i >> 14, e = i & 16383;
    ((u32*)(hnext + (size_t)l*RINGN*HSLOT))[e] = 0u;
  }
  if (i == 0) *done = 0;
}

// ---------------- helpers ----------------
__device__ __forceinline__ int poll_agent(const int* q) {
  int v;
  for (;;) {
    v = __hip_atomic_load(q, __ATOMIC_RELAXED, __HIP_MEMORY_SCOPE_AGENT);
    if (__all(v != 0)) break;
    __builtin_amdgcn_s_sleep(1);
  }
  return v;
}
__device__ __forceinline__ int ld_flag_l(const int* p) {       // sc0: L1-bypass L2 read
  int v;
  asm volatile("global_load_dword %0, %1, off sc0\n\ts_waitcnt vmcnt(0)"
               : "=v"(v) : "v"(p) : "memory");
  return v;
}
__device__ __forceinline__ f16x8 ld_a_l(const f16* p) {        // 16B same-XCD L2 load
  f16x8 v;
  asm volatile("global_load_dwordx4 %0, %1, off sc0" : "=v"(v) : "v"(p));
  return v;
}
__device__ __forceinline__ f16x8 ld_a_p(const f16* p) {        // 16B plain cached load
  f16x8 v;
  asm volatile("global_load_dwordx4 %0, %1, off" : "=v"(v) : "v"(p));
  return v;
}
__device__ __forceinline__ f16x8 ldA_coh(const f16* p) {       // cross-XCD via MALL (proven)
  union { u64 q[2]; f16x8 v; } u;
  u.q[0] = __hip_atomic_load((const u64*)p,     __ATOMIC_RELAXED, __HIP_MEMORY_SCOPE_AGENT);
  u.q[1] = __hip_atomic_load((const u64*)p + 1, __ATOMIC_RELAXED, __HIP_MEMORY_SCOPE_AGENT);
  return u.v;
}
__device__ __forceinline__ void st_h_l(f16* p, short s) {      // plain store -> own-XCD L2
  asm volatile("global_store_short %0, %1, off" :: "v"(p), "v"((int)s) : "memory");
}
__device__ __forceinline__ void st_flag_plain(int* p, int v) {
  asm volatile("global_store_dword %0, %1, off" :: "v"(p), "v"(v) : "memory");
}
__device__ __forceinline__ void vm_wait(int n) {
  if (n == 0)      asm volatile("s_waitcnt vmcnt(0)" ::: "memory");
  else if (n == 8) asm volatile("s_waitcnt vmcnt(8)" ::: "memory");
  __builtin_amdgcn_sched_barrier(0);
}
__device__ __forceinline__ float sigf(float x) {
  return __builtin_amdgcn_rcpf(1.f + __expf(-x));
}
__device__ __forceinline__ float tanhf_(float x) {
  float e = __expf(-2.f*fabsf(x));
  float r = (1.f - e) * __builtin_amdgcn_rcpf(1.f + e);
  return x < 0.f ? -r : r;
}

// grid = 256 (1 block/CU via 128KB dynLDS). bid<128 & layer<6: R10 pipeline (UNCHANGED).
// All other blocks: MFMA heater — keeps the SMU at max GFX clock while the latency-bound
// pipeline runs (VALUBusy ~5% alone lets the clock collapse to the idle DPM state, which
// multiplies every sync-hop latency). Heaters exit when done==96 (posted by working WGs);
// no working WG ever waits on a heater -> no liveness risk.
__global__ __launch_bounds__(256, 1)
void lstm_pipeline(const f16* __restrict__ xcat, const f16* __restrict__ wlds,
                   const f16* __restrict__ wreg, const float* __restrict__ bias,
                   f16* hnext, f16* hloc, int* flagL, int* flagN, int* done,
                   float* __restrict__ rnn_out) {
  const int bid = blockIdx.x;
  const int layer = bid & 7, sub = bid >> 3;
  if (bid >= 128 || layer >= 6) {
    // ---- heater: dense MFMA spin on registers, periodic done check ----
    f16x8 ha;
    #pragma unroll
    for (int j = 0; j < 8; ++j) ha[j] = (f16)1.0f;
    f32x4 hc0 = (f32x4){0,0,0,0}, hc1 = (f32x4){0,0,0,0};
    f32x4 hc2 = (f32x4){0,0,0,0}, hc3 = (f32x4){0,0,0,0};
    for (u32 it = 0;; ++it) {
      #pragma unroll
      for (int j = 0; j < 16; ++j) {
        hc0 = __builtin_amdgcn_mfma_f32_16x16x32_f16(ha, ha, hc0, 0,0,0);
        hc1 = __builtin_amdgcn_mfma_f32_16x16x32_f16(ha, ha, hc1, 0,0,0);
        hc2 = __builtin_amdgcn_mfma_f32_16x16x32_f16(ha, ha, hc2, 0,0,0);
        hc3 = __builtin_amdgcn_mfma_f32_16x16x32_f16(ha, ha, hc3, 0,0,0);
      }
      if ((it & 31) == 31) {
        if (__hip_atomic_load(done, __ATOMIC_RELAXED, __HIP_MEMORY_SCOPE_AGENT) >= 96)
          break;
      }
    }
    asm volatile("" :: "v"(hc0), "v"(hc1), "v"(hc2), "v"(hc3));
    return;
  }
  const int rg = sub >> 2, ug = sub & 3;
  extern __shared__ char smem[];
  const int stack = layer/3, level = layer - stack*3;

  { // input-half weights -> LDS (swizzled image, 128KB linear copy)
    const uint4* src = (const uint4*)(wlds + (size_t)(layer*4 + ug)*256*256);
    uint4* dst = (uint4*)smem;
    for (int i = threadIdx.x; i < 8192; i += 256) dst[i] = src[i];
  }
  const int lane = threadIdx.x & 63, wv = threadIdx.x >> 6;
  const int lc = lane & 15, akg = lane >> 4;
  const int slot4 = rg*4 + (lane & 3);             // replicated poll slot (4 ug producers)
  const int xcp1 = ((int)__builtin_amdgcn_s_getreg((31 << 11) | 20) & 7) + 1;  // XCC_ID+1

  // rec-half B into registers (128 VGPR/lane, resident for the whole run)
  f16x8 Brec[4][8];
  {
    const f16* wr = wreg + ((size_t)(layer*4 + ug)*4 + wv)*4*8*512;
    #pragma unroll
    for (int g = 0; g < 4; ++g)
      #pragma unroll
      for (int ks = 0; ks < 8; ++ks)
        Brec[g][ks] = *(const f16x8*)(wr + ((size_t)(g*8 + ks)*64 + lane)*8);
  }
  float bI, bJ, bF, bO;
  {
    const float* bb = bias + (size_t)(layer*4 + ug)*256 + wv*16 + lc;
    bI = bb[0*64]; bJ = bb[1*64]; bF = bb[2*64]; bO = bb[3*64];
  }
  __syncthreads();

  const size_t FL = (size_t)(TSTEPS+1)*16;
  int*       flL  = flagL + (size_t)layer*FL;
  int*       flN  = flagN + (size_t)layer*FL;
  const int* flNp = flagN + (size_t)(layer-1)*FL;
  const int* flNn = flagN + (size_t)(layer+1)*FL;

  const size_t aoff = (size_t)(rg*32 + lc)*256 + (size_t)akg*8;  // A frag base (+mt*4096)
  const int ucol = ug*64 + wv*16 + lc;                           // this lane's unit column

  float c_st[2][4], hmx[2][4];
  #pragma unroll
  for (int mt = 0; mt < 2; ++mt)
    #pragma unroll
    for (int r = 0; r < 4; ++r) { c_st[mt][r] = 0.f; hmx[mt][r] = -2.f; }

  f16x8 aI[2][8];
  f32x4 acc[2][4];
  int prev_ok = 0;
  bool prev_l2 = false;

#define LOAD_AI(T)                                                                    \
  do {                                                                                \
    if (level == 0) {                                                                 \
      const f16* A_ = xcat + (size_t)(stack ? (TSTEPS - (T)) : ((T)-1))*NB*256;       \
      _Pragma("unroll")                                                               \
      for (int mt = 0; mt < 2; ++mt)                                                  \
        _Pragma("unroll")                                                             \
        for (int ks = 0; ks < 8; ++ks)                                                \
          aI[mt][ks] = ld_a_p(A_ + aoff + mt*4096 + ks*32);                           \
    } else if (prev_l2) {                                                             \
      const f16* A_ = hloc + ((size_t)(layer-1)*RINGN + (size_t)((T) & 7))*HSLOT;     \
      _Pragma("unroll")                                                               \
      for (int mt = 0; mt < 2; ++mt)                                                  \
        _Pragma("unroll")                                                             \
        for (int ks = 0; ks < 8; ++ks)                                                \
          aI[mt][ks] = ld_a_l(A_ + aoff + mt*4096 + ks*32);                           \
    } else {                                                                          \
      const f16* A_ = hnext + ((size_t)(layer-1)*RINGN + (size_t)((T) & 7))*HSLOT;    \
      _Pragma("unroll")                                                               \
      for (int mt = 0; mt < 2; ++mt)                                                  \
        _Pragma("unroll")                                                             \
        for (int ks = 0; ks < 8; ++ks)                                                \
          aI[mt][ks] = ldA_coh(A_ + aoff + mt*4096 + ks*32);                          \
    }                                                                                 \
  } while (0)

#define IN_GEMM()                                                                     \
  do {                                                                                \
    _Pragma("unroll")                                                                 \
    for (int mt = 0; mt < 2; ++mt)                                                    \
      _Pragma("unroll")                                                               \
      for (int g = 0; g < 4; ++g) acc[mt][g] = (f32x4){0.f,0.f,0.f,0.f};              \
    _Pragma("unroll")                                                                 \
    for (int ks = 0; ks < 8; ++ks) {                                                  \
      const int swz = (((ks*4 + akg) ^ (lc & 7)) << 4);                               \
      f16x8 vb0 = *(const f16x8*)(smem + (0*64 + wv*16 + lc)*512 + swz);              \
      f16x8 vb1 = *(const f16x8*)(smem + (1*64 + wv*16 + lc)*512 + swz);              \
      f16x8 vb2 = *(const f16x8*)(smem + (2*64 + wv*16 + lc)*512 + swz);              \
      f16x8 vb3 = *(const f16x8*)(smem + (3*64 + wv*16 + lc)*512 + swz);              \
      _Pragma("unroll")                                                               \
      for (int mt = 0; mt < 2; ++mt) {                                                \
        acc[mt][0] = __builtin_amdgcn_mfma_f32_16x16x32_f16(aI[mt][ks], vb0, acc[mt][0],0,0,0); \
        acc[mt][1] = __builtin_amdgcn_mfma_f32_16x16x32_f16(aI[mt][ks], vb1, acc[mt][1],0,0,0); \
        acc[mt][2] = __builtin_amdgcn_mfma_f32_16x16x32_f16(aI[mt][ks], vb2, acc[mt][2],0,0,0); \
        acc[mt][3] = __builtin_amdgcn_mfma_f32_16x16x32_f16(aI[mt][ks], vb3, acc[mt][3],0,0,0); \
      }                                                                               \
    }                                                                                 \
  } while (0)

  // ---- prologue: prev lookahead, aI(1), inGEMM(1) ----
  if (level) {
    int la = 4 > TSTEPS ? TSTEPS : 4;
    int v = poll_agent(flNp + (size_t)la*16 + slot4);
    prev_l2 = __all(v == xcp1);
    prev_ok = la;
  }
  LOAD_AI(1);
  vm_wait(0);
  IN_GEMM();

  for (int t = 1; t <= TSTEPS; ++t) {
    // A. own-rg poll(t-1): 4 ug flags; sc0 fast path, MALL fallback every 4th spin
    bool fast;
    {
      const int* qL = flL + (size_t)(t-1)*16 + slot4;
      const int* qN = flN + (size_t)(t-1)*16 + slot4;
      int it = 0;
      for (;;) {
        int vL = ld_flag_l(qL);
        if (__all(vL == xcp1)) { fast = true; break; }
        if ((++it & 3) == 0) {
          int vN = __hip_atomic_load(qN, __ATOMIC_RELAXED, __HIP_MEMORY_SCOPE_AGENT);
          if (__all(vN != 0)) { fast = false; break; }
        }
        __builtin_amdgcn_s_sleep(1);
      }
    }
    __builtin_amdgcn_sched_barrier(0);

    // B. issue 16 aH loads (own rg rows x all 256 units of h_{t-1})
    f16x8 aH[2][8];
    {
      const size_t hb = ((size_t)layer*RINGN + (size_t)((t-1) & 7))*HSLOT;
      if (fast) {
        const f16* A = hloc + hb;
        #pragma unroll
        for (int mt = 0; mt < 2; ++mt)
          #pragma unroll
          for (int ks = 0; ks < 8; ++ks)
            aH[mt][ks] = ld_a_l(A + aoff + mt*4096 + ks*32);
      } else {
        const f16* A = hnext + hb;
        #pragma unroll
        for (int mt = 0; mt < 2; ++mt)
          #pragma unroll
          for (int ks = 0; ks < 8; ++ks)
            aH[mt][ks] = ldA_coh(A + aoff + mt*4096 + ks*32);
      }
    }
    __builtin_amdgcn_sched_barrier(0);

    // C. amortized rg-local cross-layer polls (overlap aH flight; fan-in 4)
    if (level < 2 && t >= 8 && (t & 1) == 0)
      poll_agent(flNn + (size_t)(t-6)*16 + slot4);         // ring-8 backpressure
    if (level && t < TSTEPS && prev_ok < t + 1) {          // prev lookahead for aI(t+1)
      int la = (t + 4 <= TSTEPS) ? t + 4 : TSTEPS;
      int v = poll_agent(flNp + (size_t)la*16 + slot4);
      prev_l2 = __all(v == xcp1);
      prev_ok = la;
    }
    __builtin_amdgcn_sched_barrier(0);

    // D. wait aH (only outstanding VMEM), rec-half GEMM (acc += aH x Brec, zero LDS)
    vm_wait(0);
    #pragma unroll
    for (int ks = 0; ks < 8; ++ks)
      #pragma unroll
      for (int mt = 0; mt < 2; ++mt) {
        acc[mt][0] = __builtin_amdgcn_mfma_f32_16x16x32_f16(aH[mt][ks], Brec[0][ks], acc[mt][0],0,0,0);
        acc[mt][1] = __builtin_amdgcn_mfma_f32_16x16x32_f16(aH[mt][ks], Brec[1][ks], acc[mt][1],0,0,0);
        acc[mt][2] = __builtin_amdgcn_mfma_f32_16x16x32_f16(aH[mt][ks], Brec[2][ks], acc[mt][2],0,0,0);
        acc[mt][3] = __builtin_amdgcn_mfma_f32_16x16x32_f16(aH[mt][ks], Brec[3][ks], acc[mt][3],0,0,0);
      }
    __builtin_amdgcn_sched_barrier(0);

    // E. issue aI(t+1): FIRST into the vm queue (flies under cell + stores)
    if (t < TSTEPS) LOAD_AI(t + 1);
    __builtin_amdgcn_sched_barrier(0);

    // F. cell update (lane-local: 4 gates of unit ucol, 8 rows)
    short hh[2][4];
    #pragma unroll
    for (int mt = 0; mt < 2; ++mt) {
      #pragma unroll
      for (int r = 0; r < 4; ++r) {
        float zi = acc[mt][0][r] + bI;
        float zj = acc[mt][1][r] + bJ;
        float zf = acc[mt][2][r] + bF;               // forget +1 folded
        float zo = acc[mt][3][r] + bO;
        float cs = sigf(zf)*c_st[mt][r] + sigf(zi)*tanhf_(zj);
        c_st[mt][r] = cs;
        float h = sigf(zo)*tanhf_(cs);
        if (level == 2) hmx[mt][r] = fmaxf(hmx[mt][r], h);
        union { f16 h; short s; } cv; cv.h = (f16)h;
        hh[mt][r] = cv.s;
      }
    }

    // G. stores: 8 hloc (L2, plain) then 8 hnext (MALL, atomic)
    {
      const size_t ob = ((size_t)layer*RINGN + (size_t)(t & 7))*HSLOT;
      f16* hl = hloc  + ob;
      f16* hn = hnext + ob;
      #pragma unroll
      for (int mt = 0; mt < 2; ++mt)
        #pragma unroll
        for (int r = 0; r < 4; ++r) {
          int row = rg*32 + mt*16 + akg*4 + r;
          st_h_l(hl + (size_t)row*256 + ucol, hh[mt][r]);
        }
      __builtin_amdgcn_sched_barrier(0);
      #pragma unroll
      for (int mt = 0; mt < 2; ++mt)
        #pragma unroll
        for (int r = 0; r < 4; ++r) {
          int row = rg*32 + mt*16 + akg*4 + r;
          __hip_atomic_store((short*)(hn + (size_t)row*256 + ucol), hh[mt][r],
                             __ATOMIC_RELAXED, __HIP_MEMORY_SCOPE_AGENT);
        }
      __builtin_amdgcn_sched_barrier(0);
    }

    // H. vmcnt(8): aI(t+1)+hloc done (hnext still flying); WG barrier; ONE flagL per WG
    vm_wait(8);
    __syncthreads();
    if (threadIdx.x == 0) st_flag_plain(flL + (size_t)t*16 + rg*4 + ug, xcp1);

    // I. inGEMM(t+1) while hnext drains (aI complete per vmcnt(8))
    if (t < TSTEPS) IN_GEMM();

    // J. full drain (hnext @MALL); WG barrier; ONE flagN per WG
    vm_wait(0);
    __syncthreads();
    if (threadIdx.x == 0)
      __hip_atomic_store(flN + (size_t)t*16 + rg*4 + ug, xcp1,
                         __ATOMIC_RELAXED, __HIP_MEMORY_SCOPE_AGENT);
  }
#undef LOAD_AI
#undef IN_GEMM

  if (level == 2) {
    #pragma unroll
    for (int mt = 0; mt < 2; ++mt)
      #pragma unroll
      for (int r = 0; r < 4; ++r)
        rnn_out[(size_t)(rg*32 + mt*16 + akg*4 + r)*512 + stack*256 + ucol] = hmx[mt][r];
  }

  // ---- signal heaters: this working WG is finished ----
  __syncthreads();
  if (threadIdx.x == 0)
    __hip_atomic_fetch_add(done, 1, __ATOMIC_RELAXED, __HIP_MEMORY_SCOPE_AGENT);
}

// ---------------- epilogue: elu(rnn@W1+b1)@W2+b2 -> sigmoid ----------------
__global__ __launch_bounds__(256)
void dense_kernel(const float* __restrict__ rnn, const float* __restrict__ W1,
                  const float* __restrict__ b1, const float* __restrict__ W2,
                  const float* __restrict__ b2, float* __restrict__ out) {
  __shared__ float h1[16][64];
  int r0 = blockIdx.x*16;
  int c = threadIdx.x & 63, rr = threadIdx.x >> 6;
  #pragma unroll
  for (int m = 0; m < 4; ++m) {
    int rl = rr*4 + m;
    const float* rp = rnn + (size_t)(r0 + rl)*512;
    float s = b1[c];
    for (int k = 0; k < 512; ++k) s = fmaf(rp[k], W1[(size_t)k*64 + c], s);
    h1[rl][c] = (s > 0.f) ? s : (__expf(s) - 1.f);
  }
  __syncthreads();
  if (threadIdx.x < 96) {
    int rl = threadIdx.x/6, cc = threadIdx.x - rl*6;
    float s = b2[cc];
    #pragma unroll
    for (int k = 0; k < 64; ++k) s = fmaf(h1[rl][k], W2[k*6 + cc], s);
    out[(size_t)(r0 + rl)*6 + cc] = 1.f/(1.f + __expf(-s));
  }
}

// ---------------- launch ----------------
extern "C" void kernel_launch(void* const* d_in, const int* in_sizes, int n_in,
                              void* d_out, int out_size, void* d_ws, size_t ws_size,
                              hipStream_t stream) {
  if (ws_size < WS_NEED) return;  // clean failure instead of corruption
  const int*   words = (const int*)d_in[0];
  const int*   caps  = (const int*)d_in[1];
  const float* emb   = (const float*)d_in[2];
  const float* capt  = (const float*)d_in[3];
  char* ws = (char*)d_ws;
  f16*   xcat  = (f16*)  (ws + OFF_XCAT);
  f16*   wlds  = (f16*)  (ws + OFF_WLDS);
  f16*   wreg  = (f16*)  (ws + OFF_WREG);
  float* bias  = (float*)(ws + OFF_BIAS);
  f16*   hnext = (f16*)  (ws + OFF_HNEXT);
  f16*   hloc  = (f16*)  (ws + OFF_HLOC);
  int*   flagL = (int*)  (ws + OFF_FLAGL);
  int*   flagN = (int*)  (ws + OFF_FLAGN);
  int*   done  = (int*)  (ws + OFF_DONE);
  float* rnn   = (float*)(ws + OFF_RNN);

  embed_kernel<<<TSTEPS*NB, 256, 0, stream>>>(words, caps, emb, capt, xcat);
  pack_kernel<<<6144 + 384, 256, 0, stream>>>(
      (const float*)d_in[4],  (const float*)d_in[5],  (const float*)d_in[6],  (const float*)d_in[7],
      (const float*)d_in[8],  (const float*)d_in[9],  (const float*)d_in[10], (const float*)d_in[11],
      (const float*)d_in[12], (const float*)d_in[13], (const float*)d_in[14], (const float*)d_in[15],
      wlds, wreg, bias);
  init_kernel<<<768, 256, 0, stream>>>(flagL, flagN, hnext, done);
  lstm_pipeline<<<256, 256, 131072, stream>>>(xcat, wlds, wreg, bias, hnext, hloc,
                                              flagL, flagN, done, rnn);
  dense_kernel<<<8, 256, 0, stream>>>(rnn, (const float*)d_in[16], (const float*)d_in[17],
                                      (const float*)d_in[18], (const float*)d_in[19], (float*)d_out);
}